// Round 2
// baseline (1780.048 us; speedup 1.0000x reference)
//
#include <hip/hip_runtime.h>
#include <hip/hip_bf16.h>

// ---------------------------------------------------------------------------
// SingleHeadTransformer on MI355X (gfx950)
// x = tok_emb[idx] + pos_emb ; q,k,v = x@W* ; causal softmax(q k^T / 32) @ v ;
// logits = out @ Wo + bo
// All GEMMs: bf16 MFMA 16x16x32, 128x128 tile, BK=32, global_load_lds(16B).
// Scratch policy: everything consumed BEFORE the LM head lives in d_out
// (823 MB, fully overwritten by the final GEMM). Only WoT + ob live in d_ws
// (111.4 MB needed).
// ---------------------------------------------------------------------------

typedef __bf16 bf16x8 __attribute__((ext_vector_type(8)));
typedef __bf16 bf16x4 __attribute__((ext_vector_type(4)));
typedef float  f32x4  __attribute__((ext_vector_type(4)));

#define BM 128
#define BN 128
#define BK 32

// --- embed: x[m][c] = tok_emb[idx[m]][c] + pos_emb[m&2047][c], cast bf16 ----
__global__ void embed_kernel(const int* __restrict__ idx,
                             const float* __restrict__ tok,
                             const float* __restrict__ pos,
                             __bf16* __restrict__ x) {
    int m = blockIdx.x;              // 0..4095
    int t = m & 2047;
    int row = idx[m];
    int c = threadIdx.x * 4;         // 256 threads * 4 = 1024
    float4 a = *(const float4*)(tok + (size_t)row * 1024 + c);
    float4 p = *(const float4*)(pos + (size_t)t * 1024 + c);
    bf16x4 v;
    v[0] = (__bf16)(a.x + p.x);
    v[1] = (__bf16)(a.y + p.y);
    v[2] = (__bf16)(a.z + p.z);
    v[3] = (__bf16)(a.w + p.w);
    *(bf16x4*)(x + (size_t)m * 1024 + c) = v;
}

// --- fp32 [K][N] -> bf16 [N][K] (transpose + cast), N may be ragged --------
__global__ void transpose_cast_kernel(const float* __restrict__ in,
                                      __bf16* __restrict__ out,
                                      int K, int N) {
    __shared__ float tile[32][33];
    int n0 = blockIdx.x * 32, k0 = blockIdx.y * 32;
    int tx = threadIdx.x & 31, ty = threadIdx.x >> 5;   // 32 x 8
    #pragma unroll
    for (int s = 0; s < 32; s += 8) {
        int k = k0 + ty + s, n = n0 + tx;
        tile[ty + s][tx] = (n < N) ? in[(size_t)k * N + n] : 0.f;
    }
    __syncthreads();
    #pragma unroll
    for (int s = 0; s < 32; s += 8) {
        int n = n0 + ty + s, k = k0 + tx;
        if (n < N) out[(size_t)n * K + k] = (__bf16)tile[tx][ty + s];
    }
}

// --- bf16 [R][C] -> bf16 [C][R], batched via blockIdx.z (stride R*C) -------
__global__ void transpose_bf16_kernel(const __bf16* __restrict__ in,
                                      __bf16* __restrict__ out,
                                      int R, int C) {
    __shared__ __bf16 tile[32][33];
    size_t boff = (size_t)blockIdx.z * (size_t)R * C;
    int c0 = blockIdx.x * 32, r0 = blockIdx.y * 32;
    int tx = threadIdx.x & 31, ty = threadIdx.x >> 5;
    #pragma unroll
    for (int s = 0; s < 32; s += 8)
        tile[ty + s][tx] = in[boff + (size_t)(r0 + ty + s) * C + c0 + tx];
    __syncthreads();
    #pragma unroll
    for (int s = 0; s < 32; s += 8)
        out[boff + (size_t)(c0 + ty + s) * R + r0 + tx] = tile[tx][ty + s];
}

// --- causal row softmax: S fp32 [4096][2048] -> P bf16 (zeros above diag) --
__global__ void softmax_kernel(const float* __restrict__ S,
                               __bf16* __restrict__ P) {
    int gr = blockIdx.x;             // b*2048 + t
    int t = gr & 2047;
    const float* srow = S + (size_t)gr * 2048;
    __bf16* prow = P + (size_t)gr * 2048;
    int n = t + 1;
    const float scale = 0.03125f;    // 1024^-0.5
    int tid = threadIdx.x, lane = tid & 63, wave = tid >> 6;
    __shared__ float red[8];

    float mx = -3.0e38f;
    for (int c = tid; c < n; c += 256) mx = fmaxf(mx, srow[c]);
    #pragma unroll
    for (int o = 32; o > 0; o >>= 1) mx = fmaxf(mx, __shfl_xor(mx, o));
    if (lane == 0) red[wave] = mx;
    __syncthreads();
    mx = fmaxf(fmaxf(red[0], red[1]), fmaxf(red[2], red[3]));
    float mscaled = mx * scale;

    float sum = 0.f;
    for (int c = tid; c < n; c += 256) sum += __expf(srow[c] * scale - mscaled);
    #pragma unroll
    for (int o = 32; o > 0; o >>= 1) sum += __shfl_xor(sum, o);
    if (lane == 0) red[4 + wave] = sum;
    __syncthreads();
    sum = red[4] + red[5] + red[6] + red[7];
    float inv = 1.f / sum;

    for (int c = tid; c < 2048; c += 256) {
        float p = (c < n) ? __expf(srow[c] * scale - mscaled) * inv : 0.f;
        prow[c] = (__bf16)p;
    }
}

// --- bf16 GEMM: C = A[M,K] @ Bt[N,K]^T  (m97 structure) --------------------
// MODE 0: plain. MODE 1: skip tiles fully above causal diagonal (S = q k^T).
// MODE 2: limit K-loop to row0+BM (PV with zeroed upper-tri P).
template <bool OUT_BF16, bool ADD_BIAS, int MODE>
__global__ __launch_bounds__(256)
void gemm_bt(const __bf16* __restrict__ A, const __bf16* __restrict__ Bt,
             void* __restrict__ Cv, const float* __restrict__ bias,
             int M, int N, int K, int lda, int ldb, int ldc,
             long sA, long sB, long sC) {
    int bx = blockIdx.x, by = blockIdx.y, bz = blockIdx.z;
    int row0 = by * BM, col0 = bx * BN;
    if (MODE == 1 && col0 >= row0 + BM) return;   // fully masked tile
    int kend = K;
    if (MODE == 2) { int kl = row0 + BM; kend = (kl < K) ? kl : K; }

    A  += (size_t)bz * sA;
    Bt += (size_t)bz * sB;

    __shared__ __align__(16) __bf16 As[BM * BK];
    __shared__ __align__(16) __bf16 Bs[BN * BK];

    int tid = threadIdx.x, lane = tid & 63, wave = tid >> 6;
    int wr = wave >> 1, wc = wave & 1;            // 2x2 waves -> 64x64 each
    int r  = lane >> 2;                            // row within 16-row chunk
    int cc = (lane & 3) * 8;                       // elem offset within row

    f32x4 acc[4][4] = {};

    typedef const __attribute__((address_space(1))) unsigned int* gp_t;
    typedef __attribute__((address_space(3))) unsigned int* lp_t;

    for (int k0 = 0; k0 < kend; k0 += BK) {
        __syncthreads();
        // stage A,B tiles: 8 chunks of 1024B each; wave w takes chunks w, w+4
        for (int c = wave; c < 8; c += 4) {
            const __bf16* ga = A  + (size_t)(row0 + c * 16 + r) * lda + k0 + cc;
            const __bf16* gb = Bt + (size_t)(col0 + c * 16 + r) * ldb + k0 + cc;
            __builtin_amdgcn_global_load_lds((gp_t)(const void*)ga,
                                             (lp_t)(void*)(As + c * 512), 16, 0, 0);
            __builtin_amdgcn_global_load_lds((gp_t)(const void*)gb,
                                             (lp_t)(void*)(Bs + c * 512), 16, 0, 0);
        }
        __syncthreads();   // compiler drains vmcnt before s_barrier

        int fr = lane & 15, fk = (lane >> 4) * 8;
        bf16x8 af[4], bfr[4];
        #pragma unroll
        for (int m = 0; m < 4; ++m)
            af[m] = *(const bf16x8*)&As[(wr * 64 + m * 16 + fr) * BK + fk];
        #pragma unroll
        for (int n2 = 0; n2 < 4; ++n2)
            bfr[n2] = *(const bf16x8*)&Bs[(wc * 64 + n2 * 16 + fr) * BK + fk];
        #pragma unroll
        for (int m = 0; m < 4; ++m)
            #pragma unroll
            for (int n2 = 0; n2 < 4; ++n2)
                acc[m][n2] = __builtin_amdgcn_mfma_f32_16x16x32_bf16(
                    af[m], bfr[n2], acc[m][n2], 0, 0, 0);
    }

    // epilogue: C/D layout col = lane&15, row = (lane>>4)*4 + j
    int fr = lane & 15, fq = lane >> 4;
    #pragma unroll
    for (int m = 0; m < 4; ++m) {
        #pragma unroll
        for (int n2 = 0; n2 < 4; ++n2) {
            int colg = col0 + wc * 64 + n2 * 16 + fr;
            if (colg >= N) continue;
            float bval = ADD_BIAS ? bias[colg] : 0.f;
            #pragma unroll
            for (int j = 0; j < 4; ++j) {
                int rowg = row0 + wr * 64 + m * 16 + fq * 4 + j;
                float v = acc[m][n2][j] + bval;
                if (OUT_BF16)
                    ((__bf16*)Cv)[(size_t)bz * sC + (size_t)rowg * ldc + colg] = (__bf16)v;
                else
                    ((float*)Cv)[(size_t)bz * sC + (size_t)rowg * ldc + colg] = v;
            }
        }
    }
}

// ---------------------------------------------------------------------------
extern "C" void kernel_launch(void* const* d_in, const int* in_sizes, int n_in,
                              void* d_out, int out_size, void* d_ws, size_t ws_size,
                              hipStream_t stream) {
    const int*   idx = (const int*)  d_in[0];
    const float* tok = (const float*)d_in[1];
    const float* pos = (const float*)d_in[2];
    const float* Wk  = (const float*)d_in[3];
    const float* Wq  = (const float*)d_in[4];
    const float* Wv  = (const float*)d_in[5];
    const float* Wo  = (const float*)d_in[6];
    const float* bo  = (const float*)d_in[7];

    // --- d_ws layout (only buffers LIVE during the LM head; ~111.4 MB) -----
    //   [0, 103022592)          WoT [50304][1024] bf16 (rows >= 50257 unused)
    //   [103022592, 111411200)  ob  [4096][1024] bf16  (attention output)
    char* ws = (char*)d_ws;
    __bf16* WoT = (__bf16*)(ws);
    __bf16* ob  = (__bf16*)(ws + 103022592ull);

    // --- d_out scratch (823 MB; everything here is consumed before the LM
    //     head, which then overwrites all of d_out) -------------------------
    //   [0,32M)    S    fp32 [2][2048][2048]
    //   [32M,48M)  P    bf16 [2][2048][2048]
    //   [48M,56M)  x_bf bf16 [4096][1024]
    //   [56M,80M)  qkv  bf16 [3][4096][1024]
    //   [80M,88M)  vT   bf16 [2][1024][2048]
    //   [88M,94M)  WT   bf16 [3][1024][1024]
    char* od = (char*)d_out;
    float*  S    = (float*)od;
    __bf16* P    = (__bf16*)(od + 33554432ull);
    __bf16* x_bf = (__bf16*)(od + 50331648ull);
    __bf16* qkv  = (__bf16*)(od + 58720256ull);
    __bf16* vT   = (__bf16*)(od + 83886080ull);
    __bf16* WT   = (__bf16*)(od + 92274688ull);

    dim3 tb(256);

    // 1. weight transposes+casts (bf16 B^T layout for all GEMMs)
    transpose_cast_kernel<<<dim3(32, 32), tb, 0, stream>>>(Wq, WT,           1024, 1024);
    transpose_cast_kernel<<<dim3(32, 32), tb, 0, stream>>>(Wk, WT + 1048576, 1024, 1024);
    transpose_cast_kernel<<<dim3(32, 32), tb, 0, stream>>>(Wv, WT + 2097152, 1024, 1024);
    transpose_cast_kernel<<<dim3(1571, 32), tb, 0, stream>>>(Wo, WoT, 1024, 50257);

    // 2. embeddings
    embed_kernel<<<4096, tb, 0, stream>>>(idx, tok, pos, x_bf);

    // 3. q,k,v = x @ {Wq,Wk,Wv}   (batched over z = weight index, sA = 0)
    gemm_bt<true, false, 0><<<dim3(8, 32, 3), tb, 0, stream>>>(
        x_bf, WT, qkv, nullptr, 4096, 1024, 1024, 1024, 1024, 1024,
        0L, 1048576L, 4194304L);

    // 4. vT[b] = v[b]^T
    transpose_bf16_kernel<<<dim3(32, 64, 2), tb, 0, stream>>>(
        qkv + 2 * 4194304, vT, 2048, 1024);

    // 5. S = q @ k^T  per batch (skip fully-masked upper tiles)
    gemm_bt<false, false, 1><<<dim3(16, 16, 2), tb, 0, stream>>>(
        qkv, qkv + 4194304, S, nullptr, 2048, 2048, 1024, 1024, 1024, 2048,
        2097152L, 2097152L, 4194304L);

    // 6. P = causal softmax(S / 32), zeros above diagonal
    softmax_kernel<<<4096, tb, 0, stream>>>(S, P);

    // 7. ob = P @ v  (K-loop limited to causal extent)
    gemm_bt<true, false, 2><<<dim3(8, 16, 2), tb, 0, stream>>>(
        P, vT, ob, nullptr, 2048, 1024, 2048, 2048, 2048, 1024,
        4194304L, 2097152L, 2097152L);

    // 8. logits = ob @ Wo + bo   -> d_out fp32 [4096][50257]
    gemm_bt<false, true, 0><<<dim3(393, 32, 1), tb, 0, stream>>>(
        ob, WoT, (float*)d_out, bo, 4096, 50257, 1024, 1024, 1024, 50257,
        0L, 0L, 0L);
}